// Round 19
// baseline (142.759 us; speedup 1.0000x reference)
//
#include <hip/hip_runtime.h>
#include <hip/hip_fp16.h>
#include <math.h>

// SwinV2-3D block: RES=32, WS=8, SHIFT=4, NH=4, DIM=128, windows=64, N=512/window.
// Round 19: R18 base (142.7us best) + T5 s_setprio extended to the MFMA clusters of
// k_qkv / k_proj_ln / k_fc1 / k_fc2 (all barrier-free or pre-barrier independent-wave
// kernels = the regime where setprio paid +8% on k_attn in R18).

typedef short bf16x8 __attribute__((ext_vector_type(8)));
typedef float f32x4 __attribute__((ext_vector_type(4)));

__device__ __forceinline__ int regionOf(int wb, int a) {
    return (wb < 3) ? 0 : ((a < 4) ? 1 : 2);
}

__device__ __forceinline__ unsigned short f2bf(float f) {
    unsigned int u = __float_as_uint(f);
    u += 0x7fffu + ((u >> 16) & 1u);   // RNE
    return (unsigned short)(u >> 16);
}

// ---------------- K0: CPB bias table: BT[3375][4] = 16*sigmoid(MLP(ctab)) ----------------
__global__ void k_bias_table(const float* __restrict__ w1, const float* __restrict__ b1,
                             const float* __restrict__ w2, float* __restrict__ BT) {
    int e = blockIdx.x;                       // 0..3374
    int id = e / 225, rem = e % 225, ih = rem / 15, iw = rem % 15;
    float ct[3];
    int ids[3] = {id, ih, iw};
#pragma unroll
    for (int a = 0; a < 3; ++a) {
        float r = (float)(ids[a] - 7) * (8.0f / 7.0f);
        float s = (r > 0.f) ? 1.f : ((r < 0.f) ? -1.f : 0.f);
        ct[a] = s * log2f(fabsf(r) + 1.0f) * (1.0f / 3.0f);
    }
    int t = threadIdx.x;                      // 128 threads
    float acc[4] = {0.f, 0.f, 0.f, 0.f};
    for (int j = t; j < 512; j += 128) {
        float hv = ct[0] * w1[j * 3 + 0] + ct[1] * w1[j * 3 + 1] + ct[2] * w1[j * 3 + 2] + b1[j];
        hv = fmaxf(hv, 0.f);
#pragma unroll
        for (int h = 0; h < 4; ++h) acc[h] += hv * w2[h * 512 + j];
    }
    __shared__ float red[4][128];
#pragma unroll
    for (int h = 0; h < 4; ++h) red[h][t] = acc[h];
    __syncthreads();
    if (t < 4) {
        float s = 0.f;
        for (int i = 0; i < 128; ++i) s += red[t][i];
        BT[e * 4 + t] = 16.0f / (1.0f + expf(-s));
    }
}

// -------- K0b: expand bias+mask to fp16 B4M[type][h][n][m] (8 x 4 x 512 x 512) ----------
// type bit2/1/0 = d/h/w axis is boundary (wb==3). Interior axis -> region 0 for all.
__global__ void k_bias_expand(const float* __restrict__ BT, __half* __restrict__ B4M) {
    int idx = blockIdx.x * 256 + threadIdx.x;   // [ty][n][m] = 8*512*512 = 2097152
    int m = idx & 511, n = (idx >> 9) & 511, ty = idx >> 18;
    int an = n >> 6, bn = (n >> 3) & 7, cn = n & 7;
    int am = m >> 6, bm = (m >> 3) & 7, cm = m & 7;
    int ridx = ((an - am + 7) * 15 + (bn - bm + 7)) * 15 + (cn - cm + 7);
    float4 bv = *(const float4*)(BT + ridx * 4);
    int cq = ((ty & 4) ? ((an < 4) ? 1 : 2) : 0) * 9 +
             ((ty & 2) ? ((bn < 4) ? 1 : 2) : 0) * 3 +
             ((ty & 1) ? ((cn < 4) ? 1 : 2) : 0);
    int cm_ = ((ty & 4) ? ((am < 4) ? 1 : 2) : 0) * 9 +
              ((ty & 2) ? ((bm < 4) ? 1 : 2) : 0) * 3 +
              ((ty & 1) ? ((cm < 4) ? 1 : 2) : 0);
    float mk = (cq == cm_) ? 0.f : -100.f;
    size_t nm = (size_t)n * 512 + m;
    B4M[((size_t)(ty * 4 + 0) << 18) + nm] = __float2half(bv.x + mk);
    B4M[((size_t)(ty * 4 + 1) << 18) + nm] = __float2half(bv.y + mk);
    B4M[((size_t)(ty * 4 + 2) << 18) + nm] = __float2half(bv.z + mk);
    B4M[((size_t)(ty * 4 + 3) << 18) + nm] = __float2half(bv.w + mk);
}

// ---------------- K0d: pack weights to bf16 fragment-linear [t*KK+kk][lane][8] -----------
__device__ __forceinline__ void packw(const float* __restrict__ src, unsigned short* __restrict__ dst,
                                      int o, int K, int KK) {
    int lane_ = (o >> 3) & 63, e = o & 7, tl = o >> 9;
    int kk = tl % KK, t = tl / KK;
    int oc = t * 16 + (lane_ & 15);
    int k = kk * 32 + 8 * (lane_ >> 4) + e;
    dst[o] = f2bf(src[(size_t)oc * K + k]);
}

__global__ void k_wcvt(const float* __restrict__ w1, const float* __restrict__ w2,
                       const float* __restrict__ qw, const float* __restrict__ pw,
                       unsigned short* __restrict__ W1f, unsigned short* __restrict__ W2f,
                       unsigned short* __restrict__ Wqf, unsigned short* __restrict__ Pwf) {
    int idx = blockIdx.x * 256 + threadIdx.x;   // 65536
    packw(w1, W1f, idx, 128, 4);
    packw(w2, W2f, idx, 512, 16);
    if (idx < 49152) packw(qw, Wqf, idx, 128, 4);
    if (idx < 16384) packw(pw, Pwf, idx, 128, 4);
}

// ---------------- K1: bf16-MFMA QKV with fused roll+window gather (LDS-free) -------------
__global__ void __launch_bounds__(256) k_qkv(
    const float* __restrict__ x, const unsigned short* __restrict__ Wqf,
    const float* __restrict__ qb, const float* __restrict__ ls,
    unsigned short* __restrict__ Qb, unsigned short* __restrict__ Kb,
    unsigned short* __restrict__ Vt) {
    const int tid = threadIdx.x;
    const int wv = tid >> 6, lane = tid & 63;
    const int qL = lane & 15, g = lane >> 4;
    const int tokG = blockIdx.x * 64 + wv * 16;
    const int w = tokG >> 9, n0 = tokG & 511;
    const int wd = w >> 4, wh = (w >> 2) & 3, ww = w & 3;
    const int n = n0 + qL;
    const int a = n >> 6, b = (n >> 3) & 7, c = n & 7;
    const int od = (wd * 8 + a + 4) & 31, oh = (wh * 8 + b + 4) & 31, ow = (ww * 8 + c + 4) & 31;
    const float* xrow = x + ((od * 32 + oh) * 32 + ow) * 128;

    bf16x8 bX[4];
#pragma unroll
    for (int kk = 0; kk < 4; ++kk) {
        float4 f0 = *(const float4*)(xrow + kk * 32 + 8 * g);
        float4 f1 = *(const float4*)(xrow + kk * 32 + 8 * g + 4);
        bf16x8 v;
        v[0] = (short)f2bf(f0.x); v[1] = (short)f2bf(f0.y);
        v[2] = (short)f2bf(f0.z); v[3] = (short)f2bf(f0.w);
        v[4] = (short)f2bf(f1.x); v[5] = (short)f2bf(f1.y);
        v[6] = (short)f2bf(f1.z); v[7] = (short)f2bf(f1.w);
        bX[kk] = v;
    }

    // ---- q,k slabs ----
#pragma unroll
    for (int s = 0; s < 2; ++s) {
        unsigned short* dst = s ? Kb : Qb;
#pragma unroll
        for (int ci = 0; ci < 4; ++ci) {
            const int ch0 = s * 128 + ci * 32;
            const int tileL = ch0 >> 4;
            f32x4 aL = {0.f, 0.f, 0.f, 0.f}, aH = {0.f, 0.f, 0.f, 0.f};
            __builtin_amdgcn_s_setprio(1);
#pragma unroll
            for (int kk = 0; kk < 4; ++kk) {
                bf16x8 wL = *(const bf16x8*)(Wqf + (size_t)(tileL * 4 + kk) * 512 + lane * 8);
                bf16x8 wH = *(const bf16x8*)(Wqf + (size_t)((tileL + 1) * 4 + kk) * 512 + lane * 8);
                aL = __builtin_amdgcn_mfma_f32_16x16x32_bf16(wL, bX[kk], aL, 0, 0, 0);
                aH = __builtin_amdgcn_mfma_f32_16x16x32_bf16(wH, bX[kk], aH, 0, 0, 0);
            }
            __builtin_amdgcn_s_setprio(0);
            float4 bL = *(const float4*)(qb + ch0 + 4 * g);
            float4 bH = *(const float4*)(qb + ch0 + 16 + 4 * g);
            float vL[4], vH[4], ss = 0.f;
#pragma unroll
            for (int r = 0; r < 4; ++r) {
                vL[r] = aL[r] + ((const float*)&bL)[r];
                vH[r] = aH[r] + ((const float*)&bH)[r];
                ss += vL[r] * vL[r] + vH[r] * vH[r];
            }
            ss += __shfl_xor(ss, 16);
            ss += __shfl_xor(ss, 32);
            float rn = 1.0f / (sqrtf(ss) + 1e-12f);
            if (s == 0) rn *= expf(fminf(ls[ci], 4.6051701859880914f));
            unsigned int l0 = (unsigned int)f2bf(vL[0] * rn) | ((unsigned int)f2bf(vL[1] * rn) << 16);
            unsigned int l1 = (unsigned int)f2bf(vL[2] * rn) | ((unsigned int)f2bf(vL[3] * rn) << 16);
            unsigned int h0 = (unsigned int)f2bf(vH[0] * rn) | ((unsigned int)f2bf(vH[1] * rn) << 16);
            unsigned int h1 = (unsigned int)f2bf(vH[2] * rn) | ((unsigned int)f2bf(vH[3] * rn) << 16);
            size_t base = ((size_t)(w * 4 + ci) * 512 + n) * 32;
            *(uint2*)(dst + base + 4 * g) = make_uint2(l0, l1);
            *(uint2*)(dst + base + 16 + 4 * g) = make_uint2(h0, h1);
        }
    }
    // ---- v slab: scatter to interleaved Vt[(n>>3)][d][n&7] ----
#pragma unroll
    for (int ci = 0; ci < 4; ++ci) {
        const int ch0 = 256 + ci * 32;
        const int tileL = ch0 >> 4;
        f32x4 aL = {0.f, 0.f, 0.f, 0.f}, aH = {0.f, 0.f, 0.f, 0.f};
        __builtin_amdgcn_s_setprio(1);
#pragma unroll
        for (int kk = 0; kk < 4; ++kk) {
            bf16x8 wL = *(const bf16x8*)(Wqf + (size_t)(tileL * 4 + kk) * 512 + lane * 8);
            bf16x8 wH = *(const bf16x8*)(Wqf + (size_t)((tileL + 1) * 4 + kk) * 512 + lane * 8);
            aL = __builtin_amdgcn_mfma_f32_16x16x32_bf16(wL, bX[kk], aL, 0, 0, 0);
            aH = __builtin_amdgcn_mfma_f32_16x16x32_bf16(wH, bX[kk], aH, 0, 0, 0);
        }
        __builtin_amdgcn_s_setprio(0);
        float4 bL = *(const float4*)(qb + ch0 + 4 * g);
        float4 bH = *(const float4*)(qb + ch0 + 16 + 4 * g);
        const size_t vtb = (size_t)(w * 4 + ci) * 32 * 512;
        const size_t nblk = (size_t)(n >> 3) * 256 + (n & 7);
#pragma unroll
        for (int r = 0; r < 4; ++r) {
            Vt[vtb + nblk + (size_t)(4 * g + r) * 8] = f2bf(aL[r] + ((const float*)&bL)[r]);
            Vt[vtb + nblk + (size_t)(16 + 4 * g + r) * 8] = f2bf(aH[r] + ((const float*)&bH)[r]);
        }
    }
}

// ---------------- K2: bf16-MFMA flash attention (emits bf16 AOb) ----------------
// grid 2048 x 256, XCD-swizzled. 4 chunks of 128 m; fused bias+mask staged in LDS;
// V interleaved. s_setprio(1) around MFMA clusters (T5; barrier-free blocks).
__global__ void __launch_bounds__(256) k_attn(
    const unsigned short* __restrict__ Qb, const unsigned short* __restrict__ Kb,
    const unsigned short* __restrict__ Vt, const __half* __restrict__ B4M,
    unsigned short* __restrict__ AOb) {
    const int bid = blockIdx.x;
    const int cxd = bid & 7;
    const int r9 = bid >> 3;
    const int qoct = r9 & 7;
    const int gidx = (r9 >> 3) * 8 + cxd;
    const int h = gidx & 3;
    const int w = gidx >> 2;
    const int tid = threadIdx.x;
    const int wv = tid >> 6;
    const int lane = tid & 63;
    const int qL = lane & 15;
    const int g = lane >> 4;

    __shared__ __align__(16) unsigned short Pbuf[4][16][136];
    __shared__ __align__(16) __half Bstage[4][16][136];

    const int q0 = qoct * 64 + wv * 16;
    const int wh4 = w * 4 + h;
    const size_t qk_base = (size_t)wh4 * 512 * 32;
    const size_t vt_base = (size_t)wh4 * 32 * 512;

    bf16x8 bQ = *(const bf16x8*)(Qb + qk_base + (size_t)(q0 + qL) * 32 + 8 * g);

    const int ty = (((w >> 4) == 3) ? 4 : 0) | ((((w >> 2) & 3) == 3) ? 2 : 0) | (((w & 3) == 3) ? 1 : 0);
    const __half* Bw = B4M + (((size_t)(ty * 4 + h) << 18)) + (size_t)q0 * 512;
    unsigned short* prow = &Pbuf[wv][qL][0];
    const __half* brow = &Bstage[wv][qL][0];

    float m_run = -1e30f, l_run = 0.f;
    f32x4 o0 = {0.f, 0.f, 0.f, 0.f}, o1 = {0.f, 0.f, 0.f, 0.f};

    for (int c = 0; c < 4; ++c) {
        const int m0 = c * 128;
        float4 br[4];
#pragma unroll
        for (int i = 0; i < 4; ++i) {
            int f = i * 64 + lane;
            br[i] = *(const float4*)(Bw + (size_t)(f >> 4) * 512 + m0 + (f & 15) * 8);
        }

        f32x4 st[8];
        __builtin_amdgcn_s_setprio(1);
#pragma unroll
        for (int t = 0; t < 8; ++t) {
            bf16x8 aK = *(const bf16x8*)(Kb + qk_base + (size_t)(m0 + t * 16 + qL) * 32 + 8 * g);
            st[t] = __builtin_amdgcn_mfma_f32_16x16x32_bf16(
                aK, bQ, (f32x4){0.f, 0.f, 0.f, 0.f}, 0, 0, 0);
        }
        __builtin_amdgcn_s_setprio(0);
#pragma unroll
        for (int i = 0; i < 4; ++i) {
            int f = i * 64 + lane;
            *(float4*)&Bstage[wv][f >> 4][(f & 15) * 8] = br[i];
        }
        float cmax = -1e30f;
#pragma unroll
        for (int t = 0; t < 8; ++t) {
            float2 braw = *(const float2*)(brow + t * 16 + 4 * g);
            __half2 h01 = *reinterpret_cast<const __half2*>(&braw.x);
            __half2 h23 = *reinterpret_cast<const __half2*>(&braw.y);
            float2 b01 = __half22float2(h01);
            float2 b23 = __half22float2(h23);
            float bvv[4] = {b01.x, b01.y, b23.x, b23.y};
#pragma unroll
            for (int r = 0; r < 4; ++r) {
                float sv = st[t][r] + bvv[r];
                st[t][r] = sv;
                cmax = fmaxf(cmax, sv);
            }
        }
        cmax = fmaxf(cmax, __shfl_xor(cmax, 16));
        cmax = fmaxf(cmax, __shfl_xor(cmax, 32));
        float mnew = fmaxf(m_run, cmax);
        float corr = __expf(m_run - mnew);
        float csum = 0.f;
#pragma unroll
        for (int t = 0; t < 8; ++t) {
#pragma unroll
            for (int r = 0; r < 4; ++r) {
                float p = __expf(st[t][r] - mnew);
                st[t][r] = p;
                csum += p;
            }
        }
        csum += __shfl_xor(csum, 16);
        csum += __shfl_xor(csum, 32);
        l_run = l_run * corr + csum;
        m_run = mnew;
#pragma unroll
        for (int r = 0; r < 4; ++r) {
            float cr = __shfl(corr, 4 * g + r, 64);
            o0[r] *= cr;
            o1[r] *= cr;
        }
#pragma unroll
        for (int t = 0; t < 8; ++t) {
            unsigned int lo = (unsigned int)f2bf(st[t][0]) | ((unsigned int)f2bf(st[t][1]) << 16);
            unsigned int hi = (unsigned int)f2bf(st[t][2]) | ((unsigned int)f2bf(st[t][3]) << 16);
            *(uint2*)(prow + t * 16 + 4 * g) = make_uint2(lo, hi);
        }
        __builtin_amdgcn_s_setprio(1);
#pragma unroll
        for (int s = 0; s < 4; ++s) {
            const size_t vblk = vt_base + (size_t)(((m0 + s * 32) >> 3) + g) * 256;
            bf16x8 pa = *(const bf16x8*)(prow + s * 32 + 8 * g);
            bf16x8 bv0 = *(const bf16x8*)(Vt + vblk + (size_t)qL * 8);
            bf16x8 bv1 = *(const bf16x8*)(Vt + vblk + (size_t)(16 + qL) * 8);
            o0 = __builtin_amdgcn_mfma_f32_16x16x32_bf16(pa, bv0, o0, 0, 0, 0);
            o1 = __builtin_amdgcn_mfma_f32_16x16x32_bf16(pa, bv1, o1, 0, 0, 0);
        }
        __builtin_amdgcn_s_setprio(0);
    }
    float linv = 1.0f / l_run;
#pragma unroll
    for (int r = 0; r < 4; ++r) {
        float lr = __shfl(linv, 4 * g + r, 64);
        int q = q0 + 4 * g + r;
        AOb[(size_t)(w * 512 + q) * 128 + h * 32 + qL] = f2bf(o0[r] * lr);
        AOb[(size_t)(w * 512 + q) * 128 + h * 32 + 16 + qL] = f2bf(o1[r] * lr);
    }
}

// ---------------- K3: bf16-MFMA proj + LN(norm1) + residual, scatter (+bf16 Xb) ---------
__global__ void __launch_bounds__(256) k_proj_ln(
    const unsigned short* __restrict__ AOb, const unsigned short* __restrict__ Pwf,
    const float* __restrict__ pb, const float* __restrict__ n1w, const float* __restrict__ n1b,
    const float* __restrict__ x, float* __restrict__ out, unsigned short* __restrict__ Xb) {
    const int tid = threadIdx.x;
    const int wv = tid >> 6, lane = tid & 63;
    const int qL = lane & 15, g = lane >> 4;
    const int tokG = blockIdx.x * 64 + wv * 16;
    const int tok = tokG + qL;
    const int w = tokG >> 9;
    const int n = (tokG & 511) + qL;
    const int wd = w >> 4, wh = (w >> 2) & 3, ww = w & 3;

    bf16x8 bA[4];
#pragma unroll
    for (int kk = 0; kk < 4; ++kk)
        bA[kk] = *(const bf16x8*)(AOb + (size_t)tok * 128 + kk * 32 + 8 * g);

    f32x4 acc[8];
#pragma unroll
    for (int t = 0; t < 8; ++t) acc[t] = (f32x4){0.f, 0.f, 0.f, 0.f};
    __builtin_amdgcn_s_setprio(1);
#pragma unroll
    for (int t = 0; t < 8; ++t) {
#pragma unroll
        for (int kk = 0; kk < 4; ++kk) {
            bf16x8 wf = *(const bf16x8*)(Pwf + (size_t)(t * 4 + kk) * 512 + lane * 8);
            acc[t] = __builtin_amdgcn_mfma_f32_16x16x32_bf16(wf, bA[kk], acc[t], 0, 0, 0);
        }
    }
    __builtin_amdgcn_s_setprio(0);

    float y[8][4];
    float s = 0.f, ssq = 0.f;
#pragma unroll
    for (int t = 0; t < 8; ++t) {
        float4 pbv = *(const float4*)(pb + t * 16 + 4 * g);
#pragma unroll
        for (int r = 0; r < 4; ++r) {
            float v = acc[t][r] + ((const float*)&pbv)[r];
            y[t][r] = v;
            s += v;
            ssq += v * v;
        }
    }
    s += __shfl_xor(s, 16);
    s += __shfl_xor(s, 32);
    ssq += __shfl_xor(ssq, 16);
    ssq += __shfl_xor(ssq, 32);
    float mean = s * (1.0f / 128.0f);
    float var = ssq * (1.0f / 128.0f) - mean * mean;
    float rstd = rsqrtf(var + 1e-5f);

    int a = n >> 6, b = (n >> 3) & 7, c = n & 7;
    int od = (wd * 8 + a + 4) & 31, oh = (wh * 8 + b + 4) & 31, ow = (ww * 8 + c + 4) & 31;
    int off = ((od * 32 + oh) * 32 + ow) * 128;
#pragma unroll
    for (int t = 0; t < 8; ++t) {
        int col = t * 16 + 4 * g;
        float4 wn = *(const float4*)(n1w + col);
        float4 bn = *(const float4*)(n1b + col);
        float4 xr = *(const float4*)(x + off + col);
        float4 o;
        o.x = xr.x + (y[t][0] - mean) * rstd * wn.x + bn.x;
        o.y = xr.y + (y[t][1] - mean) * rstd * wn.y + bn.y;
        o.z = xr.z + (y[t][2] - mean) * rstd * wn.z + bn.z;
        o.w = xr.w + (y[t][3] - mean) * rstd * wn.w + bn.w;
        *(float4*)(out + off + col) = o;
        unsigned int p0 = (unsigned int)f2bf(o.x) | ((unsigned int)f2bf(o.y) << 16);
        unsigned int p1 = (unsigned int)f2bf(o.z) | ((unsigned int)f2bf(o.w) << 16);
        *(uint2*)(Xb + off + col) = make_uint2(p0, p1);
    }
}

// ---------------- K4a: fc1 + gelu -> Hb bf16 [tok][512] ----------------
__global__ void __launch_bounds__(256) k_fc1(
    const unsigned short* __restrict__ Xb, const unsigned short* __restrict__ W1f,
    const float* __restrict__ b1f, unsigned short* __restrict__ Hb) {
    const int tid = threadIdx.x;
    const int wv = tid >> 6, lane = tid & 63;
    const int qL = lane & 15, g = lane >> 4;
    const int tok = blockIdx.x * 64 + wv * 16 + qL;
    const int ocbase = blockIdx.y * 256;

    bf16x8 bX[4];
#pragma unroll
    for (int kk = 0; kk < 4; ++kk)
        bX[kk] = *(const bf16x8*)(Xb + (size_t)tok * 128 + kk * 32 + 8 * g);

#pragma unroll
    for (int t = 0; t < 16; ++t) {
        const int oc0 = ocbase + t * 16;
        const int tile = (ocbase >> 4) + t;
        f32x4 a1 = {0.f, 0.f, 0.f, 0.f};
        __builtin_amdgcn_s_setprio(1);
#pragma unroll
        for (int kk = 0; kk < 4; ++kk) {
            bf16x8 w1v = *(const bf16x8*)(W1f + (size_t)(tile * 4 + kk) * 512 + lane * 8);
            a1 = __builtin_amdgcn_mfma_f32_16x16x32_bf16(w1v, bX[kk], a1, 0, 0, 0);
        }
        __builtin_amdgcn_s_setprio(0);
        float4 b1v = *(const float4*)(b1f + oc0 + 4 * g);
        unsigned short hb[4];
#pragma unroll
        for (int r = 0; r < 4; ++r) {
            float v = a1[r] + ((const float*)&b1v)[r];
            float u = 0.7978845608028654f * (v + 0.044715f * v * v * v);
            u = fminf(u, 15.0f);
            float e = __expf(2.0f * u);
            hb[r] = f2bf(v * e / (e + 1.0f));
        }
        unsigned int lo = (unsigned int)hb[0] | ((unsigned int)hb[1] << 16);
        unsigned int hi = (unsigned int)hb[2] | ((unsigned int)hb[3] << 16);
        *(uint2*)(Hb + (size_t)tok * 512 + oc0 + 4 * g) = make_uint2(lo, hi);
    }
}

// ---------------- K4b: fc2 (split-k) + LN(norm2) + residual ----------------
__global__ void __launch_bounds__(256) k_fc2(
    const unsigned short* __restrict__ Hb, const unsigned short* __restrict__ W2f,
    const float* __restrict__ b2f, const float* __restrict__ n2w,
    const float* __restrict__ n2b, float* __restrict__ out) {
    const int tid = threadIdx.x;
    const int wv = tid >> 6, lane = tid & 63;
    const int qL = lane & 15, g = lane >> 4;
    const int tg = wv >> 1;
    const int kh = wv & 1;
    const int tok = blockIdx.x * 32 + tg * 16 + qL;

    __shared__ __align__(16) float P[2][16][132];

    bf16x8 bH[8];
#pragma unroll
    for (int kk = 0; kk < 8; ++kk)
        bH[kk] = *(const bf16x8*)(Hb + (size_t)tok * 512 + kh * 256 + kk * 32 + 8 * g);

    f32x4 accM[8];
#pragma unroll
    for (int t = 0; t < 8; ++t) accM[t] = (f32x4){0.f, 0.f, 0.f, 0.f};
    __builtin_amdgcn_s_setprio(1);
#pragma unroll
    for (int t2 = 0; t2 < 8; ++t2) {
#pragma unroll
        for (int kk = 0; kk < 8; ++kk) {
            bf16x8 w2v = *(const bf16x8*)(W2f + (size_t)(t2 * 16 + kh * 8 + kk) * 512 + lane * 8);
            accM[t2] = __builtin_amdgcn_mfma_f32_16x16x32_bf16(w2v, bH[kk], accM[t2], 0, 0, 0);
        }
    }
    __builtin_amdgcn_s_setprio(0);

    if (kh == 1) {
#pragma unroll
        for (int t2 = 0; t2 < 8; ++t2)
            *(float4*)&P[tg][qL][t2 * 16 + 4 * g] = *(float4*)&accM[t2];
    }
    __syncthreads();
    if (kh == 0) {
        float y[8][4];
        float s = 0.f, ssq = 0.f;
#pragma unroll
        for (int t2 = 0; t2 < 8; ++t2) {
            float4 pv = *(const float4*)&P[tg][qL][t2 * 16 + 4 * g];
            float4 b2v = *(const float4*)(b2f + t2 * 16 + 4 * g);
#pragma unroll
            for (int r = 0; r < 4; ++r) {
                float v = accM[t2][r] + ((const float*)&pv)[r] + ((const float*)&b2v)[r];
                y[t2][r] = v;
                s += v;
                ssq += v * v;
            }
        }
        s += __shfl_xor(s, 16);
        s += __shfl_xor(s, 32);
        ssq += __shfl_xor(ssq, 16);
        ssq += __shfl_xor(ssq, 32);
        float mean = s * (1.0f / 128.0f);
        float var = ssq * (1.0f / 128.0f) - mean * mean;
        float rstd = rsqrtf(var + 1e-5f);
#pragma unroll
        for (int t2 = 0; t2 < 8; ++t2) {
            const int oc = t2 * 16 + 4 * g;
            float4 wn = *(const float4*)(n2w + oc);
            float4 bn = *(const float4*)(n2b + oc);
            float4 xr = *(const float4*)(out + (size_t)tok * 128 + oc);
            float4 o;
            o.x = xr.x + (y[t2][0] - mean) * rstd * wn.x + bn.x;
            o.y = xr.y + (y[t2][1] - mean) * rstd * wn.y + bn.y;
            o.z = xr.z + (y[t2][2] - mean) * rstd * wn.z + bn.z;
            o.w = xr.w + (y[t2][3] - mean) * rstd * wn.w + bn.w;
            *(float4*)(out + (size_t)tok * 128 + oc) = o;
        }
    }
}

extern "C" void kernel_launch(void* const* d_in, const int* in_sizes, int n_in, void* d_out,
                              int out_size, void* d_ws, size_t ws_size, hipStream_t stream) {
    const float* x   = (const float*)d_in[0];
    const float* n1w = (const float*)d_in[1];
    const float* n1b = (const float*)d_in[2];
    const float* qw  = (const float*)d_in[3];
    const float* qb  = (const float*)d_in[4];
    const float* ls  = (const float*)d_in[5];
    const float* cw1 = (const float*)d_in[6];
    const float* cb1 = (const float*)d_in[7];
    const float* cw2 = (const float*)d_in[8];
    const float* pw  = (const float*)d_in[9];
    const float* pb  = (const float*)d_in[10];
    const float* n2w = (const float*)d_in[11];
    const float* n2b = (const float*)d_in[12];
    const float* w1  = (const float*)d_in[13];
    const float* b1f = (const float*)d_in[14];
    const float* w2  = (const float*)d_in[15];
    const float* b2f = (const float*)d_in[16];
    float* out = (float*)d_out;

    float* ws = (float*)d_ws;
    float* BT = ws;                                        // 13504 floats
    __half* B4M = (__half*)(ws + 13504);                   // 8388608 halves = 4194304 floats
    unsigned short* Qb  = (unsigned short*)(ws + 4207808); // 4194304 ushort = 2097152 floats
    unsigned short* Kb  = (unsigned short*)(ws + 6304960);
    unsigned short* Vt  = (unsigned short*)(ws + 8402112);
    unsigned short* AOb = (unsigned short*)(ws + 10499264);
    unsigned short* W1f = (unsigned short*)(ws + 12596416); // 65536 ushort = 32768 floats
    unsigned short* W2f = (unsigned short*)(ws + 12629184);
    unsigned short* Wqf = (unsigned short*)(ws + 12661952); // 49152 ushort = 24576 floats
    unsigned short* Pwf = (unsigned short*)(ws + 12686528); // 16384 ushort = 8192 floats
    unsigned short* Xb  = (unsigned short*)(ws + 12694720); // 4194304 ushort = 2097152 floats
    // Hb (16777216 ushort = 8388608 floats) reuses the dead Qb..AOb span after k_proj_ln.
    unsigned short* Hb  = (unsigned short*)(ws + 4207808);

    k_bias_table<<<3375, 128, 0, stream>>>(cw1, cb1, cw2, BT);
    k_bias_expand<<<8192, 256, 0, stream>>>(BT, B4M);
    k_wcvt<<<256, 256, 0, stream>>>(w1, w2, qw, pw, W1f, W2f, Wqf, Pwf);
    k_qkv<<<512, 256, 0, stream>>>(x, Wqf, qb, ls, Qb, Kb, Vt);
    k_attn<<<2048, 256, 0, stream>>>(Qb, Kb, Vt, B4M, AOb);
    k_proj_ln<<<512, 256, 0, stream>>>(AOb, Pwf, pb, n1w, n1b, x, out, Xb);
    k_fc1<<<dim3(512, 2), 256, 0, stream>>>(Xb, W1f, b1f, Hb);
    k_fc2<<<1024, 256, 0, stream>>>(Hb, W2f, b2f, n2w, n2b, out);
}

// Round 20
// 142.320 us; speedup vs baseline: 1.0031x; 1.0031x over previous
//
#include <hip/hip_runtime.h>
#include <hip/hip_fp16.h>
#include <math.h>

// SwinV2-3D block: RES=32, WS=8, SHIFT=4, NH=4, DIM=128, windows=64, N=512/window.
// Round 20: R19 base (142.7us) + T13 defer-max in k_attn: skip the online-softmax
// rescale (1 exp + 8 ds_bpermute + 8 mul on the critical path) when the chunk max
// grew by <= 8 (wave-uniform __all). P bounded by e^8, bf16-safe; exact same math
// up to normalization point (cancelled by final 1/l).

typedef short bf16x8 __attribute__((ext_vector_type(8)));
typedef float f32x4 __attribute__((ext_vector_type(4)));

__device__ __forceinline__ int regionOf(int wb, int a) {
    return (wb < 3) ? 0 : ((a < 4) ? 1 : 2);
}

__device__ __forceinline__ unsigned short f2bf(float f) {
    unsigned int u = __float_as_uint(f);
    u += 0x7fffu + ((u >> 16) & 1u);   // RNE
    return (unsigned short)(u >> 16);
}

// ---------------- K0: CPB bias table: BT[3375][4] = 16*sigmoid(MLP(ctab)) ----------------
__global__ void k_bias_table(const float* __restrict__ w1, const float* __restrict__ b1,
                             const float* __restrict__ w2, float* __restrict__ BT) {
    int e = blockIdx.x;                       // 0..3374
    int id = e / 225, rem = e % 225, ih = rem / 15, iw = rem % 15;
    float ct[3];
    int ids[3] = {id, ih, iw};
#pragma unroll
    for (int a = 0; a < 3; ++a) {
        float r = (float)(ids[a] - 7) * (8.0f / 7.0f);
        float s = (r > 0.f) ? 1.f : ((r < 0.f) ? -1.f : 0.f);
        ct[a] = s * log2f(fabsf(r) + 1.0f) * (1.0f / 3.0f);
    }
    int t = threadIdx.x;                      // 128 threads
    float acc[4] = {0.f, 0.f, 0.f, 0.f};
    for (int j = t; j < 512; j += 128) {
        float hv = ct[0] * w1[j * 3 + 0] + ct[1] * w1[j * 3 + 1] + ct[2] * w1[j * 3 + 2] + b1[j];
        hv = fmaxf(hv, 0.f);
#pragma unroll
        for (int h = 0; h < 4; ++h) acc[h] += hv * w2[h * 512 + j];
    }
    __shared__ float red[4][128];
#pragma unroll
    for (int h = 0; h < 4; ++h) red[h][t] = acc[h];
    __syncthreads();
    if (t < 4) {
        float s = 0.f;
        for (int i = 0; i < 128; ++i) s += red[t][i];
        BT[e * 4 + t] = 16.0f / (1.0f + expf(-s));
    }
}

// -------- K0b: expand bias+mask to fp16 B4M[type][h][n][m] (8 x 4 x 512 x 512) ----------
__global__ void k_bias_expand(const float* __restrict__ BT, __half* __restrict__ B4M) {
    int idx = blockIdx.x * 256 + threadIdx.x;   // [ty][n][m] = 8*512*512 = 2097152
    int m = idx & 511, n = (idx >> 9) & 511, ty = idx >> 18;
    int an = n >> 6, bn = (n >> 3) & 7, cn = n & 7;
    int am = m >> 6, bm = (m >> 3) & 7, cm = m & 7;
    int ridx = ((an - am + 7) * 15 + (bn - bm + 7)) * 15 + (cn - cm + 7);
    float4 bv = *(const float4*)(BT + ridx * 4);
    int cq = ((ty & 4) ? ((an < 4) ? 1 : 2) : 0) * 9 +
             ((ty & 2) ? ((bn < 4) ? 1 : 2) : 0) * 3 +
             ((ty & 1) ? ((cn < 4) ? 1 : 2) : 0);
    int cm_ = ((ty & 4) ? ((am < 4) ? 1 : 2) : 0) * 9 +
              ((ty & 2) ? ((bm < 4) ? 1 : 2) : 0) * 3 +
              ((ty & 1) ? ((cm < 4) ? 1 : 2) : 0);
    float mk = (cq == cm_) ? 0.f : -100.f;
    size_t nm = (size_t)n * 512 + m;
    B4M[((size_t)(ty * 4 + 0) << 18) + nm] = __float2half(bv.x + mk);
    B4M[((size_t)(ty * 4 + 1) << 18) + nm] = __float2half(bv.y + mk);
    B4M[((size_t)(ty * 4 + 2) << 18) + nm] = __float2half(bv.z + mk);
    B4M[((size_t)(ty * 4 + 3) << 18) + nm] = __float2half(bv.w + mk);
}

// ---------------- K0d: pack weights to bf16 fragment-linear [t*KK+kk][lane][8] -----------
__device__ __forceinline__ void packw(const float* __restrict__ src, unsigned short* __restrict__ dst,
                                      int o, int K, int KK) {
    int lane_ = (o >> 3) & 63, e = o & 7, tl = o >> 9;
    int kk = tl % KK, t = tl / KK;
    int oc = t * 16 + (lane_ & 15);
    int k = kk * 32 + 8 * (lane_ >> 4) + e;
    dst[o] = f2bf(src[(size_t)oc * K + k]);
}

__global__ void k_wcvt(const float* __restrict__ w1, const float* __restrict__ w2,
                       const float* __restrict__ qw, const float* __restrict__ pw,
                       unsigned short* __restrict__ W1f, unsigned short* __restrict__ W2f,
                       unsigned short* __restrict__ Wqf, unsigned short* __restrict__ Pwf) {
    int idx = blockIdx.x * 256 + threadIdx.x;   // 65536
    packw(w1, W1f, idx, 128, 4);
    packw(w2, W2f, idx, 512, 16);
    if (idx < 49152) packw(qw, Wqf, idx, 128, 4);
    if (idx < 16384) packw(pw, Pwf, idx, 128, 4);
}

// ---------------- K1: bf16-MFMA QKV with fused roll+window gather (LDS-free) -------------
__global__ void __launch_bounds__(256) k_qkv(
    const float* __restrict__ x, const unsigned short* __restrict__ Wqf,
    const float* __restrict__ qb, const float* __restrict__ ls,
    unsigned short* __restrict__ Qb, unsigned short* __restrict__ Kb,
    unsigned short* __restrict__ Vt) {
    const int tid = threadIdx.x;
    const int wv = tid >> 6, lane = tid & 63;
    const int qL = lane & 15, g = lane >> 4;
    const int tokG = blockIdx.x * 64 + wv * 16;
    const int w = tokG >> 9, n0 = tokG & 511;
    const int wd = w >> 4, wh = (w >> 2) & 3, ww = w & 3;
    const int n = n0 + qL;
    const int a = n >> 6, b = (n >> 3) & 7, c = n & 7;
    const int od = (wd * 8 + a + 4) & 31, oh = (wh * 8 + b + 4) & 31, ow = (ww * 8 + c + 4) & 31;
    const float* xrow = x + ((od * 32 + oh) * 32 + ow) * 128;

    bf16x8 bX[4];
#pragma unroll
    for (int kk = 0; kk < 4; ++kk) {
        float4 f0 = *(const float4*)(xrow + kk * 32 + 8 * g);
        float4 f1 = *(const float4*)(xrow + kk * 32 + 8 * g + 4);
        bf16x8 v;
        v[0] = (short)f2bf(f0.x); v[1] = (short)f2bf(f0.y);
        v[2] = (short)f2bf(f0.z); v[3] = (short)f2bf(f0.w);
        v[4] = (short)f2bf(f1.x); v[5] = (short)f2bf(f1.y);
        v[6] = (short)f2bf(f1.z); v[7] = (short)f2bf(f1.w);
        bX[kk] = v;
    }

    // ---- q,k slabs ----
#pragma unroll
    for (int s = 0; s < 2; ++s) {
        unsigned short* dst = s ? Kb : Qb;
#pragma unroll
        for (int ci = 0; ci < 4; ++ci) {
            const int ch0 = s * 128 + ci * 32;
            const int tileL = ch0 >> 4;
            f32x4 aL = {0.f, 0.f, 0.f, 0.f}, aH = {0.f, 0.f, 0.f, 0.f};
            __builtin_amdgcn_s_setprio(1);
#pragma unroll
            for (int kk = 0; kk < 4; ++kk) {
                bf16x8 wL = *(const bf16x8*)(Wqf + (size_t)(tileL * 4 + kk) * 512 + lane * 8);
                bf16x8 wH = *(const bf16x8*)(Wqf + (size_t)((tileL + 1) * 4 + kk) * 512 + lane * 8);
                aL = __builtin_amdgcn_mfma_f32_16x16x32_bf16(wL, bX[kk], aL, 0, 0, 0);
                aH = __builtin_amdgcn_mfma_f32_16x16x32_bf16(wH, bX[kk], aH, 0, 0, 0);
            }
            __builtin_amdgcn_s_setprio(0);
            float4 bL = *(const float4*)(qb + ch0 + 4 * g);
            float4 bH = *(const float4*)(qb + ch0 + 16 + 4 * g);
            float vL[4], vH[4], ss = 0.f;
#pragma unroll
            for (int r = 0; r < 4; ++r) {
                vL[r] = aL[r] + ((const float*)&bL)[r];
                vH[r] = aH[r] + ((const float*)&bH)[r];
                ss += vL[r] * vL[r] + vH[r] * vH[r];
            }
            ss += __shfl_xor(ss, 16);
            ss += __shfl_xor(ss, 32);
            float rn = 1.0f / (sqrtf(ss) + 1e-12f);
            if (s == 0) rn *= expf(fminf(ls[ci], 4.6051701859880914f));
            unsigned int l0 = (unsigned int)f2bf(vL[0] * rn) | ((unsigned int)f2bf(vL[1] * rn) << 16);
            unsigned int l1 = (unsigned int)f2bf(vL[2] * rn) | ((unsigned int)f2bf(vL[3] * rn) << 16);
            unsigned int h0 = (unsigned int)f2bf(vH[0] * rn) | ((unsigned int)f2bf(vH[1] * rn) << 16);
            unsigned int h1 = (unsigned int)f2bf(vH[2] * rn) | ((unsigned int)f2bf(vH[3] * rn) << 16);
            size_t base = ((size_t)(w * 4 + ci) * 512 + n) * 32;
            *(uint2*)(dst + base + 4 * g) = make_uint2(l0, l1);
            *(uint2*)(dst + base + 16 + 4 * g) = make_uint2(h0, h1);
        }
    }
    // ---- v slab: scatter to interleaved Vt[(n>>3)][d][n&7] ----
#pragma unroll
    for (int ci = 0; ci < 4; ++ci) {
        const int ch0 = 256 + ci * 32;
        const int tileL = ch0 >> 4;
        f32x4 aL = {0.f, 0.f, 0.f, 0.f}, aH = {0.f, 0.f, 0.f, 0.f};
        __builtin_amdgcn_s_setprio(1);
#pragma unroll
        for (int kk = 0; kk < 4; ++kk) {
            bf16x8 wL = *(const bf16x8*)(Wqf + (size_t)(tileL * 4 + kk) * 512 + lane * 8);
            bf16x8 wH = *(const bf16x8*)(Wqf + (size_t)((tileL + 1) * 4 + kk) * 512 + lane * 8);
            aL = __builtin_amdgcn_mfma_f32_16x16x32_bf16(wL, bX[kk], aL, 0, 0, 0);
            aH = __builtin_amdgcn_mfma_f32_16x16x32_bf16(wH, bX[kk], aH, 0, 0, 0);
        }
        __builtin_amdgcn_s_setprio(0);
        float4 bL = *(const float4*)(qb + ch0 + 4 * g);
        float4 bH = *(const float4*)(qb + ch0 + 16 + 4 * g);
        const size_t vtb = (size_t)(w * 4 + ci) * 32 * 512;
        const size_t nblk = (size_t)(n >> 3) * 256 + (n & 7);
#pragma unroll
        for (int r = 0; r < 4; ++r) {
            Vt[vtb + nblk + (size_t)(4 * g + r) * 8] = f2bf(aL[r] + ((const float*)&bL)[r]);
            Vt[vtb + nblk + (size_t)(16 + 4 * g + r) * 8] = f2bf(aH[r] + ((const float*)&bH)[r]);
        }
    }
}

// ---------------- K2: bf16-MFMA flash attention (emits bf16 AOb) ----------------
// grid 2048 x 256, XCD-swizzled. 4 chunks of 128 m; fused bias+mask staged in LDS;
// V interleaved; setprio around MFMA; defer-max (THR=8) skips the rescale block.
__global__ void __launch_bounds__(256) k_attn(
    const unsigned short* __restrict__ Qb, const unsigned short* __restrict__ Kb,
    const unsigned short* __restrict__ Vt, const __half* __restrict__ B4M,
    unsigned short* __restrict__ AOb) {
    const int bid = blockIdx.x;
    const int cxd = bid & 7;
    const int r9 = bid >> 3;
    const int qoct = r9 & 7;
    const int gidx = (r9 >> 3) * 8 + cxd;
    const int h = gidx & 3;
    const int w = gidx >> 2;
    const int tid = threadIdx.x;
    const int wv = tid >> 6;
    const int lane = tid & 63;
    const int qL = lane & 15;
    const int g = lane >> 4;

    __shared__ __align__(16) unsigned short Pbuf[4][16][136];
    __shared__ __align__(16) __half Bstage[4][16][136];

    const int q0 = qoct * 64 + wv * 16;
    const int wh4 = w * 4 + h;
    const size_t qk_base = (size_t)wh4 * 512 * 32;
    const size_t vt_base = (size_t)wh4 * 32 * 512;

    bf16x8 bQ = *(const bf16x8*)(Qb + qk_base + (size_t)(q0 + qL) * 32 + 8 * g);

    const int ty = (((w >> 4) == 3) ? 4 : 0) | ((((w >> 2) & 3) == 3) ? 2 : 0) | (((w & 3) == 3) ? 1 : 0);
    const __half* Bw = B4M + (((size_t)(ty * 4 + h) << 18)) + (size_t)q0 * 512;
    unsigned short* prow = &Pbuf[wv][qL][0];
    const __half* brow = &Bstage[wv][qL][0];

    float m_run = -1e30f, l_run = 0.f;
    f32x4 o0 = {0.f, 0.f, 0.f, 0.f}, o1 = {0.f, 0.f, 0.f, 0.f};

    for (int c = 0; c < 4; ++c) {
        const int m0 = c * 128;
        float4 br[4];
#pragma unroll
        for (int i = 0; i < 4; ++i) {
            int f = i * 64 + lane;
            br[i] = *(const float4*)(Bw + (size_t)(f >> 4) * 512 + m0 + (f & 15) * 8);
        }

        f32x4 st[8];
        __builtin_amdgcn_s_setprio(1);
#pragma unroll
        for (int t = 0; t < 8; ++t) {
            bf16x8 aK = *(const bf16x8*)(Kb + qk_base + (size_t)(m0 + t * 16 + qL) * 32 + 8 * g);
            st[t] = __builtin_amdgcn_mfma_f32_16x16x32_bf16(
                aK, bQ, (f32x4){0.f, 0.f, 0.f, 0.f}, 0, 0, 0);
        }
        __builtin_amdgcn_s_setprio(0);
#pragma unroll
        for (int i = 0; i < 4; ++i) {
            int f = i * 64 + lane;
            *(float4*)&Bstage[wv][f >> 4][(f & 15) * 8] = br[i];
        }
        float cmax = -1e30f;
#pragma unroll
        for (int t = 0; t < 8; ++t) {
            float2 braw = *(const float2*)(brow + t * 16 + 4 * g);
            __half2 h01 = *reinterpret_cast<const __half2*>(&braw.x);
            __half2 h23 = *reinterpret_cast<const __half2*>(&braw.y);
            float2 b01 = __half22float2(h01);
            float2 b23 = __half22float2(h23);
            float bvv[4] = {b01.x, b01.y, b23.x, b23.y};
#pragma unroll
            for (int r = 0; r < 4; ++r) {
                float sv = st[t][r] + bvv[r];
                st[t][r] = sv;
                cmax = fmaxf(cmax, sv);
            }
        }
        cmax = fmaxf(cmax, __shfl_xor(cmax, 16));
        cmax = fmaxf(cmax, __shfl_xor(cmax, 32));
        // T13 defer-max: skip rescale when the max grew <= 8 for ALL q-rows of this wave.
        const bool skip = __all(cmax <= m_run + 8.0f);
        float mnew = skip ? m_run : fmaxf(m_run, cmax);
        float csum = 0.f;
#pragma unroll
        for (int t = 0; t < 8; ++t) {
#pragma unroll
            for (int r = 0; r < 4; ++r) {
                float p = __expf(st[t][r] - mnew);
                st[t][r] = p;
                csum += p;
            }
        }
        csum += __shfl_xor(csum, 16);
        csum += __shfl_xor(csum, 32);
        if (skip) {
            l_run += csum;
        } else {
            float corr = __expf(m_run - mnew);
            l_run = l_run * corr + csum;
            m_run = mnew;
#pragma unroll
            for (int r = 0; r < 4; ++r) {
                float cr = __shfl(corr, 4 * g + r, 64);
                o0[r] *= cr;
                o1[r] *= cr;
            }
        }
#pragma unroll
        for (int t = 0; t < 8; ++t) {
            unsigned int lo = (unsigned int)f2bf(st[t][0]) | ((unsigned int)f2bf(st[t][1]) << 16);
            unsigned int hi = (unsigned int)f2bf(st[t][2]) | ((unsigned int)f2bf(st[t][3]) << 16);
            *(uint2*)(prow + t * 16 + 4 * g) = make_uint2(lo, hi);
        }
        __builtin_amdgcn_s_setprio(1);
#pragma unroll
        for (int s = 0; s < 4; ++s) {
            const size_t vblk = vt_base + (size_t)(((m0 + s * 32) >> 3) + g) * 256;
            bf16x8 pa = *(const bf16x8*)(prow + s * 32 + 8 * g);
            bf16x8 bv0 = *(const bf16x8*)(Vt + vblk + (size_t)qL * 8);
            bf16x8 bv1 = *(const bf16x8*)(Vt + vblk + (size_t)(16 + qL) * 8);
            o0 = __builtin_amdgcn_mfma_f32_16x16x32_bf16(pa, bv0, o0, 0, 0, 0);
            o1 = __builtin_amdgcn_mfma_f32_16x16x32_bf16(pa, bv1, o1, 0, 0, 0);
        }
        __builtin_amdgcn_s_setprio(0);
    }
    float linv = 1.0f / l_run;
#pragma unroll
    for (int r = 0; r < 4; ++r) {
        float lr = __shfl(linv, 4 * g + r, 64);
        int q = q0 + 4 * g + r;
        AOb[(size_t)(w * 512 + q) * 128 + h * 32 + qL] = f2bf(o0[r] * lr);
        AOb[(size_t)(w * 512 + q) * 128 + h * 32 + 16 + qL] = f2bf(o1[r] * lr);
    }
}

// ---------------- K3: bf16-MFMA proj + LN(norm1) + residual, scatter (+bf16 Xb) ---------
__global__ void __launch_bounds__(256) k_proj_ln(
    const unsigned short* __restrict__ AOb, const unsigned short* __restrict__ Pwf,
    const float* __restrict__ pb, const float* __restrict__ n1w, const float* __restrict__ n1b,
    const float* __restrict__ x, float* __restrict__ out, unsigned short* __restrict__ Xb) {
    const int tid = threadIdx.x;
    const int wv = tid >> 6, lane = tid & 63;
    const int qL = lane & 15, g = lane >> 4;
    const int tokG = blockIdx.x * 64 + wv * 16;
    const int tok = tokG + qL;
    const int w = tokG >> 9;
    const int n = (tokG & 511) + qL;
    const int wd = w >> 4, wh = (w >> 2) & 3, ww = w & 3;

    bf16x8 bA[4];
#pragma unroll
    for (int kk = 0; kk < 4; ++kk)
        bA[kk] = *(const bf16x8*)(AOb + (size_t)tok * 128 + kk * 32 + 8 * g);

    f32x4 acc[8];
#pragma unroll
    for (int t = 0; t < 8; ++t) acc[t] = (f32x4){0.f, 0.f, 0.f, 0.f};
    __builtin_amdgcn_s_setprio(1);
#pragma unroll
    for (int t = 0; t < 8; ++t) {
#pragma unroll
        for (int kk = 0; kk < 4; ++kk) {
            bf16x8 wf = *(const bf16x8*)(Pwf + (size_t)(t * 4 + kk) * 512 + lane * 8);
            acc[t] = __builtin_amdgcn_mfma_f32_16x16x32_bf16(wf, bA[kk], acc[t], 0, 0, 0);
        }
    }
    __builtin_amdgcn_s_setprio(0);

    float y[8][4];
    float s = 0.f, ssq = 0.f;
#pragma unroll
    for (int t = 0; t < 8; ++t) {
        float4 pbv = *(const float4*)(pb + t * 16 + 4 * g);
#pragma unroll
        for (int r = 0; r < 4; ++r) {
            float v = acc[t][r] + ((const float*)&pbv)[r];
            y[t][r] = v;
            s += v;
            ssq += v * v;
        }
    }
    s += __shfl_xor(s, 16);
    s += __shfl_xor(s, 32);
    ssq += __shfl_xor(ssq, 16);
    ssq += __shfl_xor(ssq, 32);
    float mean = s * (1.0f / 128.0f);
    float var = ssq * (1.0f / 128.0f) - mean * mean;
    float rstd = rsqrtf(var + 1e-5f);

    int a = n >> 6, b = (n >> 3) & 7, c = n & 7;
    int od = (wd * 8 + a + 4) & 31, oh = (wh * 8 + b + 4) & 31, ow = (ww * 8 + c + 4) & 31;
    int off = ((od * 32 + oh) * 32 + ow) * 128;
#pragma unroll
    for (int t = 0; t < 8; ++t) {
        int col = t * 16 + 4 * g;
        float4 wn = *(const float4*)(n1w + col);
        float4 bn = *(const float4*)(n1b + col);
        float4 xr = *(const float4*)(x + off + col);
        float4 o;
        o.x = xr.x + (y[t][0] - mean) * rstd * wn.x + bn.x;
        o.y = xr.y + (y[t][1] - mean) * rstd * wn.y + bn.y;
        o.z = xr.z + (y[t][2] - mean) * rstd * wn.z + bn.z;
        o.w = xr.w + (y[t][3] - mean) * rstd * wn.w + bn.w;
        *(float4*)(out + off + col) = o;
        unsigned int p0 = (unsigned int)f2bf(o.x) | ((unsigned int)f2bf(o.y) << 16);
        unsigned int p1 = (unsigned int)f2bf(o.z) | ((unsigned int)f2bf(o.w) << 16);
        *(uint2*)(Xb + off + col) = make_uint2(p0, p1);
    }
}

// ---------------- K4a: fc1 + gelu -> Hb bf16 [tok][512] ----------------
__global__ void __launch_bounds__(256) k_fc1(
    const unsigned short* __restrict__ Xb, const unsigned short* __restrict__ W1f,
    const float* __restrict__ b1f, unsigned short* __restrict__ Hb) {
    const int tid = threadIdx.x;
    const int wv = tid >> 6, lane = tid & 63;
    const int qL = lane & 15, g = lane >> 4;
    const int tok = blockIdx.x * 64 + wv * 16 + qL;
    const int ocbase = blockIdx.y * 256;

    bf16x8 bX[4];
#pragma unroll
    for (int kk = 0; kk < 4; ++kk)
        bX[kk] = *(const bf16x8*)(Xb + (size_t)tok * 128 + kk * 32 + 8 * g);

#pragma unroll
    for (int t = 0; t < 16; ++t) {
        const int oc0 = ocbase + t * 16;
        const int tile = (ocbase >> 4) + t;
        f32x4 a1 = {0.f, 0.f, 0.f, 0.f};
        __builtin_amdgcn_s_setprio(1);
#pragma unroll
        for (int kk = 0; kk < 4; ++kk) {
            bf16x8 w1v = *(const bf16x8*)(W1f + (size_t)(tile * 4 + kk) * 512 + lane * 8);
            a1 = __builtin_amdgcn_mfma_f32_16x16x32_bf16(w1v, bX[kk], a1, 0, 0, 0);
        }
        __builtin_amdgcn_s_setprio(0);
        float4 b1v = *(const float4*)(b1f + oc0 + 4 * g);
        unsigned short hb[4];
#pragma unroll
        for (int r = 0; r < 4; ++r) {
            float v = a1[r] + ((const float*)&b1v)[r];
            float u = 0.7978845608028654f * (v + 0.044715f * v * v * v);
            u = fminf(u, 15.0f);
            float e = __expf(2.0f * u);
            hb[r] = f2bf(v * e / (e + 1.0f));
        }
        unsigned int lo = (unsigned int)hb[0] | ((unsigned int)hb[1] << 16);
        unsigned int hi = (unsigned int)hb[2] | ((unsigned int)hb[3] << 16);
        *(uint2*)(Hb + (size_t)tok * 512 + oc0 + 4 * g) = make_uint2(lo, hi);
    }
}

// ---------------- K4b: fc2 (split-k) + LN(norm2) + residual ----------------
__global__ void __launch_bounds__(256) k_fc2(
    const unsigned short* __restrict__ Hb, const unsigned short* __restrict__ W2f,
    const float* __restrict__ b2f, const float* __restrict__ n2w,
    const float* __restrict__ n2b, float* __restrict__ out) {
    const int tid = threadIdx.x;
    const int wv = tid >> 6, lane = tid & 63;
    const int qL = lane & 15, g = lane >> 4;
    const int tg = wv >> 1;
    const int kh = wv & 1;
    const int tok = blockIdx.x * 32 + tg * 16 + qL;

    __shared__ __align__(16) float P[2][16][132];

    bf16x8 bH[8];
#pragma unroll
    for (int kk = 0; kk < 8; ++kk)
        bH[kk] = *(const bf16x8*)(Hb + (size_t)tok * 512 + kh * 256 + kk * 32 + 8 * g);

    f32x4 accM[8];
#pragma unroll
    for (int t = 0; t < 8; ++t) accM[t] = (f32x4){0.f, 0.f, 0.f, 0.f};
    __builtin_amdgcn_s_setprio(1);
#pragma unroll
    for (int t2 = 0; t2 < 8; ++t2) {
#pragma unroll
        for (int kk = 0; kk < 8; ++kk) {
            bf16x8 w2v = *(const bf16x8*)(W2f + (size_t)(t2 * 16 + kh * 8 + kk) * 512 + lane * 8);
            accM[t2] = __builtin_amdgcn_mfma_f32_16x16x32_bf16(w2v, bH[kk], accM[t2], 0, 0, 0);
        }
    }
    __builtin_amdgcn_s_setprio(0);

    if (kh == 1) {
#pragma unroll
        for (int t2 = 0; t2 < 8; ++t2)
            *(float4*)&P[tg][qL][t2 * 16 + 4 * g] = *(float4*)&accM[t2];
    }
    __syncthreads();
    if (kh == 0) {
        float y[8][4];
        float s = 0.f, ssq = 0.f;
#pragma unroll
        for (int t2 = 0; t2 < 8; ++t2) {
            float4 pv = *(const float4*)&P[tg][qL][t2 * 16 + 4 * g];
            float4 b2v = *(const float4*)(b2f + t2 * 16 + 4 * g);
#pragma unroll
            for (int r = 0; r < 4; ++r) {
                float v = accM[t2][r] + ((const float*)&pv)[r] + ((const float*)&b2v)[r];
                y[t2][r] = v;
                s += v;
                ssq += v * v;
            }
        }
        s += __shfl_xor(s, 16);
        s += __shfl_xor(s, 32);
        ssq += __shfl_xor(ssq, 16);
        ssq += __shfl_xor(ssq, 32);
        float mean = s * (1.0f / 128.0f);
        float var = ssq * (1.0f / 128.0f) - mean * mean;
        float rstd = rsqrtf(var + 1e-5f);
#pragma unroll
        for (int t2 = 0; t2 < 8; ++t2) {
            const int oc = t2 * 16 + 4 * g;
            float4 wn = *(const float4*)(n2w + oc);
            float4 bn = *(const float4*)(n2b + oc);
            float4 xr = *(const float4*)(out + (size_t)tok * 128 + oc);
            float4 o;
            o.x = xr.x + (y[t2][0] - mean) * rstd * wn.x + bn.x;
            o.y = xr.y + (y[t2][1] - mean) * rstd * wn.y + bn.y;
            o.z = xr.z + (y[t2][2] - mean) * rstd * wn.z + bn.z;
            o.w = xr.w + (y[t2][3] - mean) * rstd * wn.w + bn.w;
            *(float4*)(out + (size_t)tok * 128 + oc) = o;
        }
    }
}

extern "C" void kernel_launch(void* const* d_in, const int* in_sizes, int n_in, void* d_out,
                              int out_size, void* d_ws, size_t ws_size, hipStream_t stream) {
    const float* x   = (const float*)d_in[0];
    const float* n1w = (const float*)d_in[1];
    const float* n1b = (const float*)d_in[2];
    const float* qw  = (const float*)d_in[3];
    const float* qb  = (const float*)d_in[4];
    const float* ls  = (const float*)d_in[5];
    const float* cw1 = (const float*)d_in[6];
    const float* cb1 = (const float*)d_in[7];
    const float* cw2 = (const float*)d_in[8];
    const float* pw  = (const float*)d_in[9];
    const float* pb  = (const float*)d_in[10];
    const float* n2w = (const float*)d_in[11];
    const float* n2b = (const float*)d_in[12];
    const float* w1  = (const float*)d_in[13];
    const float* b1f = (const float*)d_in[14];
    const float* w2  = (const float*)d_in[15];
    const float* b2f = (const float*)d_in[16];
    float* out = (float*)d_out;

    float* ws = (float*)d_ws;
    float* BT = ws;                                        // 13504 floats
    __half* B4M = (__half*)(ws + 13504);                   // 8388608 halves = 4194304 floats
    unsigned short* Qb  = (unsigned short*)(ws + 4207808); // 4194304 ushort = 2097152 floats
    unsigned short* Kb  = (unsigned short*)(ws + 6304960);
    unsigned short* Vt  = (unsigned short*)(ws + 8402112);
    unsigned short* AOb = (unsigned short*)(ws + 10499264);
    unsigned short* W1f = (unsigned short*)(ws + 12596416); // 65536 ushort = 32768 floats
    unsigned short* W2f = (unsigned short*)(ws + 12629184);
    unsigned short* Wqf = (unsigned short*)(ws + 12661952); // 49152 ushort = 24576 floats
    unsigned short* Pwf = (unsigned short*)(ws + 12686528); // 16384 ushort = 8192 floats
    unsigned short* Xb  = (unsigned short*)(ws + 12694720); // 4194304 ushort = 2097152 floats
    // Hb (16777216 ushort = 8388608 floats) reuses the dead Qb..AOb span after k_proj_ln.
    unsigned short* Hb  = (unsigned short*)(ws + 4207808);

    k_bias_table<<<3375, 128, 0, stream>>>(cw1, cb1, cw2, BT);
    k_bias_expand<<<8192, 256, 0, stream>>>(BT, B4M);
    k_wcvt<<<256, 256, 0, stream>>>(w1, w2, qw, pw, W1f, W2f, Wqf, Pwf);
    k_qkv<<<512, 256, 0, stream>>>(x, Wqf, qb, ls, Qb, Kb, Vt);
    k_attn<<<2048, 256, 0, stream>>>(Qb, Kb, Vt, B4M, AOb);
    k_proj_ln<<<512, 256, 0, stream>>>(AOb, Pwf, pb, n1w, n1b, x, out, Xb);
    k_fc1<<<dim3(512, 2), 256, 0, stream>>>(Xb, W1f, b1f, Hb);
    k_fc2<<<1024, 256, 0, stream>>>(Hb, W2f, b2f, n2w, n2b, out);
}